// Round 4
// baseline (117.200 us; speedup 1.0000x reference)
//
#include <hip/hip_runtime.h>
#include <math.h>

// DSVF via exact time-domain IIR (== reference's FFT overlap-add: pole
// radius r <= 0.55 robustly; warm-up truncation 0.55^32 ~ 5e-9 relative,
// ~1e-7 absolute vs 1.6e-2 tolerance).
//
// R8: LDS-pipe diet. R7 (zero-barrier) was NEUTRAL vs R6 -> phase/barrier
// theories dead. Budget: HBM 21.3 us, VALU ~4 us, but scalar LDS = 96
// b32 wave-ops/wave (~560 cyc) x 64 waves/CU ~ 15 us of LDS-pipe busy --
// same order as the HBM stream; measured 33 us ~ 21 + imperfect overlap
// with 15. Fix: all-b128 LDS with an XOR chunk swizzle (involution
// sigma(c) = c ^ ((c>>3)&7) on 16-B chunks; every phase's access pattern
// lands 8 lanes per 4-bank group = conflict-free for b128). 24 b128
// wave-ops replace 96 b32 -> LDS ~5 us. IIR arithmetic order unchanged.

#define N_PER_ROW (128 * 2048)     // 262144 samples per row
#define BATCH 64
#define TPB 256
#define OUT_BLK 16                 // outputs per thread
#define WARM 32                    // warm-up samples per thread
#define WTILE (64 * OUT_BLK)       // 1024 outputs per wave
#define TILE (TPB * OUT_BLK)       // 4096 outputs per block
#define TILES_PER_ROW (N_PER_ROW / TILE)   // 64
#define WCHUNKS ((WARM + WTILE) / 4)       // 264 16-B chunks per wave

typedef float vfloat4 __attribute__((ext_vector_type(4)));

// Involution on chunk index: XOR low 3 bits with the next 3 bits.
// (sigma(c)>>3 == c>>3 since only bits 0..2 change => sigma(sigma(c))==c.)
__device__ __forceinline__ int swz(int c) { return c ^ ((c >> 3) & 7); }

__global__ __launch_bounds__(256, 8) void dsvf_iir_kernel(
    const float* __restrict__ x,
    const float* __restrict__ g_p, const float* __restrict__ R_p,
    const float* __restrict__ mhp_p, const float* __restrict__ mbp_p,
    const float* __restrict__ mlp_p,
    float* __restrict__ out)
{
    __shared__ vfloat4 lds[4 * WCHUNKS];     // 4 wave-private regions, 16.9 KB

    const int b    = blockIdx.x;
    const int row  = b >> 6;                 // / TILES_PER_ROW (=64)
    const int tl   = b & (TILES_PER_ROW - 1);
    const int k    = threadIdx.x;
    const int wid  = k >> 6;                 // wave 0..3
    const int lane = k & 63;

    const size_t wbase = (size_t)row * N_PER_ROW + (size_t)tl * TILE
                       + (size_t)wid * WTILE;
    const float* __restrict__ src = x + wbase;
    vfloat4* const wlds = &lds[wid * WCHUNKS];

    // --- halo: region chunks 0..7 (global floats [wbase-32, wbase)) ---
    // sigma is identity for c<8, so slots 0..7; banks 4c..4c+3: conflict-free.
    if (lane < 8) {
        vfloat4 v;
        if (tl == 0 && wid == 0) {           // true row start: zero state
            v.x = 0.0f; v.y = 0.0f; v.z = 0.0f; v.w = 0.0f;
        } else {
            v = *(const vfloat4*)(src - WARM + 4 * lane);
        }
        wlds[lane] = v;
    }

    // --- tile staging: chunk c = 8 + 64m + lane -> slot sigma(c) ---
    // global side stays perfectly coalesced (1 KB contiguous per wave-inst).
    #pragma unroll
    for (int m = 0; m < 4; ++m) {
        vfloat4 v = *(const vfloat4*)(src + 256 * m + 4 * lane);
        wlds[swz(8 + 64 * m + lane)] = v;    // ds_write_b128, 8 lanes/group
    }

    // --- biquad coefficients (identical math to reference, fp32) ---
    const float g = g_p[0], R = R_p[0];
    const float m_hp = mhp_p[0], m_bp = mbp_p[0], m_lp = mlp_p[0];
    const float sig = 1.0f / (1.0f + expf(-g));
    const float gt  = tanf(1.5707963267948966f * sig);   // tan(pi*sig/2)
    const float Rt  = log1pf(expf(R));                   // softplus
    const float g2  = gt * gt;
    const float b0 = g2 * m_lp + gt * m_bp + m_hp;
    const float b1 = 2.0f * g2 * m_lp - 2.0f * m_hp;
    const float b2 = g2 * m_lp - gt * m_bp + m_hp;
    const float a0 = g2 + 2.0f * Rt * gt + 1.0f;
    const float a1 = 2.0f * g2 - 2.0f;
    const float a2 = g2 - 2.0f * Rt * gt + 1.0f;
    const float inv_a0 = 1.0f / a0;
    const float B0 = b0 * inv_a0, B1 = b1 * inv_a0, B2 = b2 * inv_a0;
    const float A1 = a1 * inv_a0, A2 = a2 * inv_a0;

    // --- per-thread IIR; lane L consumes region chunks [4L, 4L+12) ---
    // (no barriers anywhere: producer/consumer are the same wave; LDS ops
    //  complete in program order within a wave — R7 verified this.)
    float s1 = 0.0f, s2 = 0.0f;
    const int c0 = 4 * lane;

#define STEP_D(xx) { float y_ = fmaf(B0, (xx), s1);                 \
                     s1 = fmaf(-A1, y_, fmaf(B1, (xx), s2));        \
                     s2 = fmaf(-A2, y_, B2 * (xx)); }
#define STEP_S(xx, yy) { (yy) = fmaf(B0, (xx), s1);                 \
                     s1 = fmaf(-A1, (yy), fmaf(B1, (xx), s2));      \
                     s2 = fmaf(-A2, (yy), B2 * (xx)); }

    #pragma unroll
    for (int j = 0; j < 8; ++j) {            // warm: 8 x ds_read_b128
        vfloat4 v = wlds[swz(c0 + j)];
        STEP_D(v.x); STEP_D(v.y); STEP_D(v.z); STEP_D(v.w);
    }

    vfloat4 o[4];                             // outputs stay in VGPRs
    #pragma unroll
    for (int j = 0; j < 4; ++j) {            // main: 4 x ds_read_b128
        vfloat4 v = wlds[swz(c0 + 8 + j)];
        vfloat4 t;
        STEP_S(v.x, t.x); STEP_S(v.y, t.y);
        STEP_S(v.z, t.z); STEP_S(v.w, t.w);
        o[j] = t;
    }
#undef STEP_D
#undef STEP_S

    // --- scatter: lane L's output chunks 4L+8..4L+11 -> sigma slots ---
    // (all reads above are earlier in program order; in-order LDS pipe)
    #pragma unroll
    for (int j = 0; j < 4; ++j) {
        wlds[swz(c0 + 8 + j)] = o[j];        // ds_write_b128, 8 lanes/group
    }

    // --- coalesced nt store: chunk c = 8 + lane + 64m -> out float4 c-8 ---
    {
        vfloat4* dp = (vfloat4*)(out + wbase);
        #pragma unroll
        for (int m = 0; m < 4; ++m) {
            vfloat4 v = wlds[swz(8 + lane + 64 * m)];
            __builtin_nontemporal_store(v, &dp[lane + 64 * m]);
        }
    }
}

extern "C" void kernel_launch(void* const* d_in, const int* in_sizes, int n_in,
                              void* d_out, int out_size, void* d_ws, size_t ws_size,
                              hipStream_t stream) {
    const float* x    = (const float*)d_in[0];
    const float* g    = (const float*)d_in[1];
    const float* R    = (const float*)d_in[2];
    const float* m_hp = (const float*)d_in[3];
    const float* m_bp = (const float*)d_in[4];
    const float* m_lp = (const float*)d_in[5];
    float* out = (float*)d_out;

    dim3 block(TPB);
    dim3 grid(BATCH * TILES_PER_ROW);         // 4096 blocks
    dsvf_iir_kernel<<<grid, block, 0, stream>>>(x, g, R, m_hp, m_bp, m_lp, out);
}

// Round 5
// 116.571 us; speedup vs baseline: 1.0054x; 1.0054x over previous
//
#include <hip/hip_runtime.h>
#include <math.h>

// DSVF via exact time-domain IIR (== reference's FFT overlap-add: pole
// radius r <= 0.55 robustly; warm-up truncation 0.55^32 ~ 5e-9 relative,
// ~1e-7 absolute vs 1.6e-2 tolerance).
//
// R9: 2-tile software pipeline. R7 (no barriers) and R8 (b128+swizzle LDS)
// were both NULL -> scheduling/LDS theories dead. Remaining structural
// lever: each block-wave paid one full exposed HBM load stall per tile
// with nothing of its own to hide it under (16 sequential generations/CU).
// Now: grid 2048 = exactly 8 blocks/CU (same 32 waves/CU TLP, zero tail),
// each block does 2 consecutive tiles; tile t+1's global loads are issued
// into registers BEFORE tile t's compute and re-staged to LDS after tile
// t's reads retire (wave-private region + in-order LDS pipe => still zero
// barriers). Outputs go to their transpose slots immediately (cross-lane
// warm reads of a chunk all precede the owner's main-loop write), keeping
// VGPRs within the 64-reg budget of launch_bounds(256,8).

#define N_PER_ROW (128 * 2048)     // 262144 samples per row
#define BATCH 64
#define TPB 256
#define OUT_BLK 16                 // outputs per thread
#define WARM 32                    // warm-up samples per thread
#define WTILE (64 * OUT_BLK)       // 1024 outputs per wave
#define TILE (TPB * OUT_BLK)       // 4096 outputs per block-tile
#define TILES_PER_ROW (N_PER_ROW / TILE)     // 64
#define TILES_PER_BLK 2
#define BLKS_PER_ROW (TILES_PER_ROW / TILES_PER_BLK)  // 32
#define WCHUNKS ((WARM + WTILE) / 4)         // 264 16-B chunks per wave

typedef float vfloat4 __attribute__((ext_vector_type(4)));

// Involution on chunk index: XOR low 3 bits with the next 3 bits.
// Every access phase lands 8 lanes per 4-bank group: conflict-free b128.
__device__ __forceinline__ int swz(int c) { return c ^ ((c >> 3) & 7); }

__global__ __launch_bounds__(256, 8) void dsvf_iir_kernel(
    const float* __restrict__ x,
    const float* __restrict__ g_p, const float* __restrict__ R_p,
    const float* __restrict__ mhp_p, const float* __restrict__ mbp_p,
    const float* __restrict__ mlp_p,
    float* __restrict__ out)
{
    __shared__ vfloat4 lds[4 * WCHUNKS];     // 4 wave-private regions, 16.9 KB

    const int p    = blockIdx.x;
    const int row  = p >> 5;                 // / BLKS_PER_ROW (=32)
    const int tl0  = (p & (BLKS_PER_ROW - 1)) * TILES_PER_BLK;
    const int k    = threadIdx.x;
    const int wid  = k >> 6;                 // wave 0..3
    const int lane = k & 63;

    const size_t base0 = (size_t)row * N_PER_ROW + (size_t)tl0 * TILE
                       + (size_t)wid * WTILE;
    const float* __restrict__ src0 = x + base0;
    const float* __restrict__ src1 = src0 + TILE;   // same wave slot, next tile
    vfloat4* const wlds = &lds[wid * WCHUNKS];

    // --- tile0 loads (registers) ---
    vfloat4 a0 = *(const vfloat4*)(src0 +   0 + 4 * lane);
    vfloat4 a1 = *(const vfloat4*)(src0 + 256 + 4 * lane);
    vfloat4 a2 = *(const vfloat4*)(src0 + 512 + 4 * lane);
    vfloat4 a3 = *(const vfloat4*)(src0 + 768 + 4 * lane);
    vfloat4 ah;
    if (lane < 8) {
        if (tl0 == 0 && wid == 0) { ah = (vfloat4){0.f, 0.f, 0.f, 0.f}; }
        else                      { ah = *(const vfloat4*)(src0 - WARM + 4 * lane); }
    }

    // --- biquad coefficients (identical math to reference, fp32) ---
    const float g = g_p[0], R = R_p[0];
    const float m_hp = mhp_p[0], m_bp = mbp_p[0], m_lp = mlp_p[0];
    const float sig = 1.0f / (1.0f + expf(-g));
    const float gt  = tanf(1.5707963267948966f * sig);   // tan(pi*sig/2)
    const float Rt  = log1pf(expf(R));                   // softplus
    const float g2  = gt * gt;
    const float b0 = g2 * m_lp + gt * m_bp + m_hp;
    const float b1 = 2.0f * g2 * m_lp - 2.0f * m_hp;
    const float b2 = g2 * m_lp - gt * m_bp + m_hp;
    const float a0c = g2 + 2.0f * Rt * gt + 1.0f;
    const float a1c = 2.0f * g2 - 2.0f;
    const float a2c = g2 - 2.0f * Rt * gt + 1.0f;
    const float inv_a0 = 1.0f / a0c;
    const float B0 = b0 * inv_a0, B1 = b1 * inv_a0, B2 = b2 * inv_a0;
    const float A1 = a1c * inv_a0, A2 = a2c * inv_a0;

#define STEP_D(xx) { float y_ = fmaf(B0, (xx), s1);                 \
                     s1 = fmaf(-A1, y_, fmaf(B1, (xx), s2));        \
                     s2 = fmaf(-A2, y_, B2 * (xx)); }
#define STEP_S(xx, yy) { (yy) = fmaf(B0, (xx), s1);                 \
                     s1 = fmaf(-A1, (yy), fmaf(B1, (xx), s2));      \
                     s2 = fmaf(-A2, (yy), B2 * (xx)); }

    // compute tile from wave-private LDS region, store to dst.
    // Transpose: each output chunk is written to its swizzled slot right
    // after it's produced (all cross-lane warm reads of that chunk are in
    // the warm loop, which precedes every main-loop write; LDS is in-order
    // per wave and the region is wave-private => no barrier).
#define COMPUTE_STORE(dst) do {                                          \
        float s1 = 0.0f, s2 = 0.0f;                                      \
        const int c0 = 4 * lane;                                         \
        _Pragma("unroll")                                                \
        for (int j = 0; j < 8; ++j) {          /* warm: 8 x b128 */      \
            vfloat4 v = wlds[swz(c0 + j)];                               \
            STEP_D(v.x); STEP_D(v.y); STEP_D(v.z); STEP_D(v.w);          \
        }                                                                \
        _Pragma("unroll")                                                \
        for (int j = 0; j < 4; ++j) {          /* main: 4 x b128 */      \
            vfloat4 v = wlds[swz(c0 + 8 + j)];                           \
            vfloat4 t;                                                   \
            STEP_S(v.x, t.x); STEP_S(v.y, t.y);                          \
            STEP_S(v.z, t.z); STEP_S(v.w, t.w);                          \
            wlds[swz(c0 + 8 + j)] = t;                                   \
        }                                                                \
        vfloat4* dp = (vfloat4*)(dst);                                   \
        _Pragma("unroll")                                                \
        for (int m2 = 0; m2 < 4; ++m2) {       /* coalesced nt store */  \
            vfloat4 v = wlds[swz(8 + lane + 64 * m2)];                   \
            __builtin_nontemporal_store(v, &dp[lane + 64 * m2]);         \
        }                                                                \
    } while (0)

    // --- stage tile0 ---
    if (lane < 8) wlds[lane] = ah;             // sigma=identity for c<8
    wlds[swz(  8 + lane)] = a0;
    wlds[swz( 72 + lane)] = a1;
    wlds[swz(136 + lane)] = a2;
    wlds[swz(200 + lane)] = a3;

    // --- issue tile1 loads; they fly under tile0's compute ---
    vfloat4 b0r = *(const vfloat4*)(src1 +   0 + 4 * lane);
    vfloat4 b1r = *(const vfloat4*)(src1 + 256 + 4 * lane);
    vfloat4 b2r = *(const vfloat4*)(src1 + 512 + 4 * lane);
    vfloat4 b3r = *(const vfloat4*)(src1 + 768 + 4 * lane);
    vfloat4 bh;
    if (lane < 8) {                            // tile index >=1: never zero
        bh = *(const vfloat4*)(src1 - WARM + 4 * lane);
    }

    COMPUTE_STORE(out + base0);

    // --- stage tile1 (after all tile0 LDS reads: program order) ---
    if (lane < 8) wlds[lane] = bh;
    wlds[swz(  8 + lane)] = b0r;
    wlds[swz( 72 + lane)] = b1r;
    wlds[swz(136 + lane)] = b2r;
    wlds[swz(200 + lane)] = b3r;

    COMPUTE_STORE(out + base0 + TILE);

#undef COMPUTE_STORE
#undef STEP_D
#undef STEP_S
}

extern "C" void kernel_launch(void* const* d_in, const int* in_sizes, int n_in,
                              void* d_out, int out_size, void* d_ws, size_t ws_size,
                              hipStream_t stream) {
    const float* x    = (const float*)d_in[0];
    const float* g    = (const float*)d_in[1];
    const float* R    = (const float*)d_in[2];
    const float* m_hp = (const float*)d_in[3];
    const float* m_bp = (const float*)d_in[4];
    const float* m_lp = (const float*)d_in[5];
    float* out = (float*)d_out;

    dim3 block(TPB);
    dim3 grid(BATCH * BLKS_PER_ROW);          // 2048 blocks = 8/CU, no tail
    dsvf_iir_kernel<<<grid, block, 0, stream>>>(x, g, R, m_hp, m_bp, m_lp, out);
}